// Round 4
// baseline (3494.046 us; speedup 1.0000x reference)
//
#include <hip/hip_runtime.h>
#include <hip/hip_bf16.h>
#include <math.h>

// Problem constants
#define QLEN   512
#define MLEN   512
#define KLEN   1024
#define BSZ    8
#define NH     16
#define DH     64
#define DM     1024
#define DI     4096
#define NTOK   32000
#define NROW   4096      // QLEN*BSZ
#define XROW   8192      // KLEN*BSZ
#define VTILES 500       // 32000/64

typedef __hip_bfloat16 bf16;
typedef __attribute__((ext_vector_type(8))) short bf16x8;
typedef __attribute__((ext_vector_type(4))) float f32x4;

__device__ __forceinline__ unsigned short f2b(float x) {
    union { float f; unsigned u; } a; a.f = x;
    unsigned r = a.u + 0x7fffu + ((a.u >> 16) & 1u);
    return (unsigned short)(r >> 16);
}
__device__ __forceinline__ float b2f(unsigned short h) {
    union { unsigned u; float f; } a; a.u = ((unsigned)h) << 16;
    return a.f;
}

__device__ __forceinline__ void gload_lds16(const void* g, void* l) {
    __builtin_amdgcn_global_load_lds(
        (const __attribute__((address_space(1))) unsigned int*)g,
        (__attribute__((address_space(3))) unsigned int*)l, 16, 0, 0);
}

// ---------------------------------------------------------------------------
// Positional embedding directly in bf16: pos[j,d], pos_seq[j]=1023-j
__global__ __launch_bounds__(256) void posb_kernel(unsigned short* __restrict__ posb) {
    int j = blockIdx.x;
    int t = threadIdx.x;
    float p = (float)(1023 - j);
    #pragma unroll
    for (int u = 0; u < 4; u++) {
        int dcol = t + u * 256;
        int k = dcol & 511;
        float invf = expf(-((float)k) * (1.0f / 512.0f) * 9.210340371976184f);
        float a = p * invf;
        posb[j * DM + dcol] = f2b((dcol < 512) ? sinf(a) : cosf(a));
    }
}

// ---------------------------------------------------------------------------
// Embedding gather: out[row,:] = emb[data[row],:]; also bf16 copy for layer 0
__global__ __launch_bounds__(256) void gather_emb(const int* __restrict__ data,
                                                  const float* __restrict__ emb,
                                                  float* __restrict__ out,
                                                  unsigned short* __restrict__ outb) {
    int row = blockIdx.x;
    int t = threadIdx.x;
    int tok = data[row];
    float4 v = ((const float4*)(emb + (size_t)tok * DM))[t];
    ((float4*)(out + (size_t)row * DM))[t] = v;
    ushort4 o;
    o.x = f2b(v.x); o.y = f2b(v.y); o.z = f2b(v.z); o.w = f2b(v.w);
    ((ushort4*)(outb + (size_t)row * DM))[t] = o;
}

// ---------------------------------------------------------------------------
// fp32 -> bf16 cast, 4 elems/thread
__global__ __launch_bounds__(256) void cast_bf16(const float* __restrict__ src,
                                                 unsigned short* __restrict__ dst, int n4) {
    int i = blockIdx.x * 256 + threadIdx.x;
    if (i < n4) {
        float4 v = ((const float4*)src)[i];
        ushort4 o;
        o.x = f2b(v.x); o.y = f2b(v.y); o.z = f2b(v.z); o.w = f2b(v.w);
        ((ushort4*)dst)[i] = o;
    }
}

// ---------------------------------------------------------------------------
// fp32 [K,N] -> bf16 [N,K] transpose+cast. grid (N/32, K/32), block 256.
__global__ __launch_bounds__(256) void castT_kernel(const float* __restrict__ src,
                                                    unsigned short* __restrict__ dst,
                                                    int K, int N) {
    __shared__ float T[32][33];
    int t = threadIdx.x;
    int k0 = blockIdx.y * 32, n0 = blockIdx.x * 32;
    int r = t >> 3, c4 = (t & 7) * 4;
    float4 v = *(const float4*)(src + (size_t)(k0 + r) * N + n0 + c4);
    T[r][c4 + 0] = v.x; T[r][c4 + 1] = v.y; T[r][c4 + 2] = v.z; T[r][c4 + 3] = v.w;
    __syncthreads();
    ushort4 o;
    o.x = f2b(T[c4 + 0][r]); o.y = f2b(T[c4 + 1][r]);
    o.z = f2b(T[c4 + 2][r]); o.w = f2b(T[c4 + 3][r]);
    *(ushort4*)(dst + (size_t)(n0 + r) * K + k0 + c4) = o;
}

// ---------------------------------------------------------------------------
// bf16 MFMA GEMM: C[M,N] = A[M,K] @ B[N,K]^T. Both operands K-major bf16.
// SPLITK>1: blockIdx.z handles K-chunk z, writes fp32 partial at z*M*N.
template <bool BIAS, bool RELU, bool OUTBF16, int SPLITK = 1>
__global__ __launch_bounds__(256) void gemm_bt(const unsigned short* __restrict__ A,
                                               const unsigned short* __restrict__ B,
                                               const float* __restrict__ bias,
                                               void* __restrict__ Cout,
                                               int M, int N, int K) {
    __shared__ unsigned short As[128 * 32];
    __shared__ unsigned short Bs[128 * 32];
    int t = threadIdx.x;
    int wave = t >> 6, lane = t & 63;
    int bm = blockIdx.y * 128, bn = blockIdx.x * 128;
    int wm = (wave >> 1) * 64, wn = (wave & 1) * 64;
    int quad = lane >> 4, l16 = lane & 15;

    f32x4 acc[4][4] = {};

    int srow = wave * 32 + (lane >> 2);
    int scol = (lane & 3) * 8;
    const unsigned short* Ag = A + (size_t)(bm + srow) * K + scol;
    const unsigned short* Bg = B + (size_t)(bn + srow) * K + scol;
    unsigned short* Al0 = As + (wave * 32) * 32;
    unsigned short* Al1 = As + (wave * 32 + 16) * 32;
    unsigned short* Bl0 = Bs + (wave * 32) * 32;
    unsigned short* Bl1 = Bs + (wave * 32 + 16) * 32;

    int kchunk = K / SPLITK;
    int k0 = (SPLITK > 1) ? blockIdx.z * kchunk : 0;
    for (int kt = k0; kt < k0 + kchunk; kt += 32) {
        gload_lds16(Ag + kt, Al0);
        gload_lds16(Ag + kt + (size_t)16 * K, Al1);
        gload_lds16(Bg + kt, Bl0);
        gload_lds16(Bg + kt + (size_t)16 * K, Bl1);
        __syncthreads();
        bf16x8 af[4], bfr[4];
        #pragma unroll
        for (int mi = 0; mi < 4; mi++)
            af[mi] = *(const bf16x8*)&As[(wm + mi * 16 + l16) * 32 + quad * 8];
        #pragma unroll
        for (int ni = 0; ni < 4; ni++)
            bfr[ni] = *(const bf16x8*)&Bs[(wn + ni * 16 + l16) * 32 + quad * 8];
        #pragma unroll
        for (int mi = 0; mi < 4; mi++)
            #pragma unroll
            for (int ni = 0; ni < 4; ni++)
                acc[mi][ni] = __builtin_amdgcn_mfma_f32_16x16x32_bf16(
                    af[mi], bfr[ni], acc[mi][ni], 0, 0, 0);
        __syncthreads();
    }

    float* Cf = (float*)Cout + ((SPLITK > 1) ? (size_t)blockIdx.z * M * N : (size_t)0);
    #pragma unroll
    for (int mi = 0; mi < 4; mi++) {
        #pragma unroll
        for (int ni = 0; ni < 4; ni++) {
            int c = bn + wn + ni * 16 + l16;
            float bv = BIAS ? bias[c] : 0.0f;
            #pragma unroll
            for (int reg = 0; reg < 4; reg++) {
                int r = bm + wm + mi * 16 + quad * 4 + reg;
                float x = acc[mi][ni][reg];
                if (BIAS) x += bv;
                if (RELU) x = fmaxf(x, 0.0f);
                if (OUTBF16) ((unsigned short*)Cout)[(size_t)r * N + c] = f2b(x);
                else         Cf[(size_t)r * N + c] = x;
            }
        }
    }
}

// ---------------------------------------------------------------------------
// Fused [q|kv] GEMM with layout-scatter epilogue. A = xmemb [8192][1024] bf16
// (rows j*8+b; rows>=4096 are core rows i*8+b). B = [Wq|Wkv]^T [3072][1024].
// Grid (24, 64): bn<8 -> q cols, 8..15 -> k cols, 16..23 -> v cols.
//  q (rows>=4096 only): qw = q+rwb (bf16, 64-col-seg swizzle key i&7),
//                       qr = q+rrb (bf16 linear)
//  k: Kh[nb][1024][64] bf16, swizzle key j&7
//  v: Vth[nb][64][1024] bf16 transposed, per-128-col seg swizzle key d&7
__global__ __launch_bounds__(256) void kqv_gemm(const unsigned short* __restrict__ A,
                                                const unsigned short* __restrict__ B,
                                                const float* __restrict__ rwb,
                                                const float* __restrict__ rrb,
                                                unsigned short* __restrict__ qw,
                                                unsigned short* __restrict__ qr,
                                                unsigned short* __restrict__ Kh,
                                                unsigned short* __restrict__ Vth) {
    int cls = blockIdx.x >> 3;                 // 0=q, 1=k, 2=v
    if (cls == 0 && blockIdx.y < 32) return;   // q for memory rows: unused
    __shared__ unsigned short As[128 * 32];
    __shared__ unsigned short Bs[128 * 32];
    const int K = 1024;
    int t = threadIdx.x;
    int wave = t >> 6, lane = t & 63;
    int bm = blockIdx.y * 128, bn = blockIdx.x * 128;
    int wm = (wave >> 1) * 64, wn = (wave & 1) * 64;
    int quad = lane >> 4, l16 = lane & 15;

    f32x4 acc[4][4] = {};

    int srow = wave * 32 + (lane >> 2);
    int scol = (lane & 3) * 8;
    const unsigned short* Ag = A + (size_t)(bm + srow) * K + scol;
    const unsigned short* Bg = B + (size_t)(bn + srow) * K + scol;
    unsigned short* Al0 = As + (wave * 32) * 32;
    unsigned short* Al1 = As + (wave * 32 + 16) * 32;
    unsigned short* Bl0 = Bs + (wave * 32) * 32;
    unsigned short* Bl1 = Bs + (wave * 32 + 16) * 32;

    for (int kt = 0; kt < K; kt += 32) {
        gload_lds16(Ag + kt, Al0);
        gload_lds16(Ag + kt + (size_t)16 * K, Al1);
        gload_lds16(Bg + kt, Bl0);
        gload_lds16(Bg + kt + (size_t)16 * K, Bl1);
        __syncthreads();
        bf16x8 af[4], bfr[4];
        #pragma unroll
        for (int mi = 0; mi < 4; mi++)
            af[mi] = *(const bf16x8*)&As[(wm + mi * 16 + l16) * 32 + quad * 8];
        #pragma unroll
        for (int ni = 0; ni < 4; ni++)
            bfr[ni] = *(const bf16x8*)&Bs[(wn + ni * 16 + l16) * 32 + quad * 8];
        #pragma unroll
        for (int mi = 0; mi < 4; mi++)
            #pragma unroll
            for (int ni = 0; ni < 4; ni++)
                acc[mi][ni] = __builtin_amdgcn_mfma_f32_16x16x32_bf16(
                    af[mi], bfr[ni], acc[mi][ni], 0, 0, 0);
        __syncthreads();
    }

    if (cls == 0) {
        #pragma unroll
        for (int ni = 0; ni < 4; ni++) {
            int c = bn + wn + ni * 16 + l16;          // 0..1023
            float wv = rwb[c], rv = rrb[c];
            #pragma unroll
            for (int mi = 0; mi < 4; mi++) {
                #pragma unroll
                for (int reg = 0; reg < 4; reg++) {
                    int r = bm + wm + mi * 16 + quad * 4 + reg;
                    int row = r - 4096;               // i*8+b
                    int i = row >> 3;
                    float x = acc[mi][ni][reg];
                    qr[(size_t)row * DM + c] = f2b(x + rv);
                    qw[(size_t)row * DM + (c & ~63) + ((c & 63) ^ ((i & 7) << 3))] = f2b(x + wv);
                }
            }
        }
    } else if (cls == 1) {
        #pragma unroll
        for (int ni = 0; ni < 4; ni++) {
            int cc = bn + wn + ni * 16 + l16 - 1024;
            int d = cc & 63, hb = cc >> 6;
            #pragma unroll
            for (int mi = 0; mi < 4; mi++) {
                #pragma unroll
                for (int reg = 0; reg < 4; reg++) {
                    int r = bm + wm + mi * 16 + quad * 4 + reg;
                    int j = r >> 3, nb = hb * 8 + (r & 7);
                    Kh[(size_t)nb * 65536 + (size_t)j * 64 + (d ^ ((j & 7) << 3))] =
                        f2b(acc[mi][ni][reg]);
                }
            }
        }
    } else {
        #pragma unroll
        for (int ni = 0; ni < 4; ni++) {
            int cc = bn + wn + ni * 16 + l16 - 2048;
            int d = cc & 63, hb = cc >> 6;
            #pragma unroll
            for (int mi = 0; mi < 4; mi++) {
                #pragma unroll
                for (int reg = 0; reg < 4; reg++) {
                    int r = bm + wm + mi * 16 + quad * 4 + reg;
                    int j = r >> 3, nb = hb * 8 + (r & 7);
                    Vth[(size_t)nb * 65536 + (size_t)d * 1024
                        + (j & ~127) + ((j & 127) ^ ((d & 7) << 3))] =
                        f2b(acc[mi][ni][reg]);
                }
            }
        }
    }
}

// ---------------------------------------------------------------------------
// Fused logits + partial LSE. Grid (bm=32, bn=250) -- bm-fastest so co-resident
// blocks share one 256KB B-strip (L2) and re-read only A (8MB, L3-resident).
__global__ __launch_bounds__(256) void lse_gemm_mfma(const unsigned short* __restrict__ A,
                                                     const unsigned short* __restrict__ B,
                                                     float* __restrict__ pmax,
                                                     float* __restrict__ psum) {
    __shared__ unsigned short As[128 * 32];
    __shared__ unsigned short Bs[128 * 32];
    int t = threadIdx.x;
    int wave = t >> 6, lane = t & 63;
    int bm = blockIdx.x * 128, bn = blockIdx.y * 128;
    int wm = (wave >> 1) * 64;
    int quad = lane >> 4, l16 = lane & 15;
    const int K = 1024;

    f32x4 acc[4][4] = {};

    int srow = wave * 32 + (lane >> 2);
    int scol = (lane & 3) * 8;
    const unsigned short* Ag = A + (size_t)(bm + srow) * K + scol;
    const unsigned short* Bg = B + (size_t)(bn + srow) * K + scol;
    unsigned short* Al0 = As + (wave * 32) * 32;
    unsigned short* Al1 = As + (wave * 32 + 16) * 32;
    unsigned short* Bl0 = Bs + (wave * 32) * 32;
    unsigned short* Bl1 = Bs + (wave * 32 + 16) * 32;
    int wn = (wave & 1) * 64;

    for (int kt = 0; kt < K; kt += 32) {
        gload_lds16(Ag + kt, Al0);
        gload_lds16(Ag + kt + (size_t)16 * K, Al1);
        gload_lds16(Bg + kt, Bl0);
        gload_lds16(Bg + kt + (size_t)16 * K, Bl1);
        __syncthreads();
        bf16x8 af[4], bfr[4];
        #pragma unroll
        for (int mi = 0; mi < 4; mi++)
            af[mi] = *(const bf16x8*)&As[(wm + mi * 16 + l16) * 32 + quad * 8];
        #pragma unroll
        for (int ni = 0; ni < 4; ni++)
            bfr[ni] = *(const bf16x8*)&Bs[(wn + ni * 16 + l16) * 32 + quad * 8];
        #pragma unroll
        for (int mi = 0; mi < 4; mi++)
            #pragma unroll
            for (int ni = 0; ni < 4; ni++)
                acc[mi][ni] = __builtin_amdgcn_mfma_f32_16x16x32_bf16(
                    af[mi], bfr[ni], acc[mi][ni], 0, 0, 0);
        __syncthreads();
    }

    int vt = blockIdx.y * 2 + (wave & 1);
    #pragma unroll
    for (int mi = 0; mi < 4; mi++) {
        #pragma unroll
        for (int reg = 0; reg < 4; reg++) {
            float m = -1e30f;
            #pragma unroll
            for (int ni = 0; ni < 4; ni++) m = fmaxf(m, acc[mi][ni][reg]);
            #pragma unroll
            for (int off = 1; off < 16; off <<= 1) m = fmaxf(m, __shfl_xor(m, off, 64));
            float s = 0.0f;
            #pragma unroll
            for (int ni = 0; ni < 4; ni++) s += __expf(acc[mi][ni][reg] - m);
            #pragma unroll
            for (int off = 1; off < 16; off <<= 1) s += __shfl_xor(s, off, 64);
            if (l16 == 0) {
                int r = bm + wm + mi * 16 + quad * 4 + reg;
                pmax[(size_t)r * VTILES + vt] = m;
                psum[(size_t)r * VTILES + vt] = s;
            }
        }
    }
}

// ---------------------------------------------------------------------------
// bd_gemm: Btilde = (q + r_r_bias) @ r_k^T per head, written PRE-SHIFTED.
// B operand has row stride ldb (packed multi-layer r_k). grid (8, 32, 16), K=64.
__global__ __launch_bounds__(256) void bd_gemm(const unsigned short* __restrict__ A,
                                               const unsigned short* __restrict__ B,
                                               int ldb,
                                               unsigned short* __restrict__ Bt) {
    __shared__ unsigned short As[128 * 32];
    __shared__ unsigned short Bs[128 * 32];
    int t = threadIdx.x;
    int wave = t >> 6, lane = t & 63;
    int bm = blockIdx.y * 128, bn = blockIdx.x * 128, n = blockIdx.z;
    int wm = (wave >> 1) * 64, wn = (wave & 1) * 64;
    int quad = lane >> 4, l16 = lane & 15;
    f32x4 acc[4][4] = {};
    int srow = wave * 32 + (lane >> 2);
    int scol = (lane & 3) * 8;
    const unsigned short* Ag = A + (size_t)(bm + srow) * DM + n * 64 + scol;
    const unsigned short* Bg = B + (size_t)(bn + srow) * ldb + n * 64 + scol;
    unsigned short* Al0 = As + (wave * 32) * 32;
    unsigned short* Al1 = As + (wave * 32 + 16) * 32;
    unsigned short* Bl0 = Bs + (wave * 32) * 32;
    unsigned short* Bl1 = Bs + (wave * 32 + 16) * 32;

    #pragma unroll
    for (int kt = 0; kt < 64; kt += 32) {
        gload_lds16(Ag + kt, Al0);
        gload_lds16(Ag + kt + (size_t)16 * DM, Al1);
        gload_lds16(Bg + kt, Bl0);
        gload_lds16(Bg + kt + (size_t)16 * ldb, Bl1);
        __syncthreads();
        bf16x8 af[4], bfr[4];
        #pragma unroll
        for (int mi = 0; mi < 4; mi++)
            af[mi] = *(const bf16x8*)&As[(wm + mi * 16 + l16) * 32 + quad * 8];
        #pragma unroll
        for (int ni = 0; ni < 4; ni++)
            bfr[ni] = *(const bf16x8*)&Bs[(wn + ni * 16 + l16) * 32 + quad * 8];
        #pragma unroll
        for (int mi = 0; mi < 4; mi++)
            #pragma unroll
            for (int ni = 0; ni < 4; ni++)
                acc[mi][ni] = __builtin_amdgcn_mfma_f32_16x16x32_bf16(
                    af[mi], bfr[ni], acc[mi][ni], 0, 0, 0);
        __syncthreads();
    }

    #pragma unroll
    for (int mi = 0; mi < 4; mi++) {
        #pragma unroll
        for (int reg = 0; reg < 4; reg++) {
            int r = bm + wm + mi * 16 + quad * 4 + reg;
            int i = r >> 3;
            size_t rowbase = ((size_t)n * 4096 + r) * 1024;
            int sw = (i & 7) << 3;
            #pragma unroll
            for (int ni = 0; ni < 4; ni++) {
                int p = bn + wn + ni * 16 + l16;
                int j = p + i - 511;
                if ((unsigned)j < 1024u)
                    Bt[rowbase + (j & ~127) + ((j & 127) ^ sw)] = f2b(acc[mi][ni][reg]);
            }
        }
    }
}

// ---------------------------------------------------------------------------
// Fused flash attention, MFMA. Writes bf16 output directly.
__global__ __launch_bounds__(256) void flash_attn(const unsigned short* __restrict__ qw_b,
                                                  const unsigned short* __restrict__ Kh,
                                                  const unsigned short* __restrict__ Vth,
                                                  const unsigned short* __restrict__ Bt,
                                                  unsigned short* __restrict__ vecb) {
    int qb = blockIdx.x, b = blockIdx.y, n = blockIdx.z;
    int i0 = qb * 64, nb = n * 8 + b;
    int t = threadIdx.x, wave = t >> 6, lane = t & 63;
    int quad = lane >> 4, l16 = lane & 15;
    int wm = wave * 16;
    __shared__ unsigned short Qw_s[64 * 64];
    __shared__ unsigned short K_s[128 * 64];
    __shared__ unsigned short Vt_s[64 * 128];
    __shared__ unsigned short BD_s[64 * 128];   // aliased as P after consumption

    // stage Qw once (8KB)
    {
        const unsigned short* g = qw_b
            + (size_t)((i0 + wave * 16 + (lane >> 3)) * 8 + b) * DM + n * 64 + (lane & 7) * 8;
        unsigned short* l = Qw_s + (wave * 16) * 64;
        gload_lds16(g, l);
        gload_lds16(g + (size_t)64 * DM, l + 8 * 64);
    }

    f32x4 o[4] = {};
    float m_run[4] = { -1e30f, -1e30f, -1e30f, -1e30f };
    float l_run[4] = {};

    int nt = ((i0 + 575) >> 7) + 1;
    for (int jt = 0; jt < nt; jt++) {
        int j0 = jt * 128;
        __syncthreads();
        {   // K tile (16KB): rows wave*32..+32
            const unsigned short* g = Kh + (size_t)nb * 65536
                + (size_t)(j0 + wave * 32 + (lane >> 3)) * 64 + (lane & 7) * 8;
            unsigned short* l = K_s + (wave * 32) * 64;
            #pragma unroll
            for (int k = 0; k < 4; k++)
                gload_lds16(g + (size_t)k * 512, l + k * 512);
        }
        {   // Vt tile (16KB): d-rows wave*16..+16
            const unsigned short* g = Vth + (size_t)nb * 65536
                + (size_t)(wave * 16 + (lane >> 4)) * 1024 + j0 + (lane & 15) * 8;
            unsigned short* l = Vt_s + (wave * 16) * 128;
            #pragma unroll
            for (int k = 0; k < 4; k++)
                gload_lds16(g + (size_t)k * 4096, l + k * 512);
        }
        {   // BD tile (16KB): q-rows wave*16..+16
            const unsigned short* g = Bt
                + ((size_t)n * 4096 + (size_t)(i0 + wave * 16 + (lane >> 4)) * 8 + b) * 1024
                + j0 + (lane & 15) * 8;
            unsigned short* l = BD_s + (wave * 16) * 128;
            #pragma unroll
            for (int k = 0; k < 4; k++)
                gload_lds16(g + (size_t)k * 32768, l + k * 512);
        }
        __syncthreads();

        // AC = Qw @ K^T
        int arow = wm + l16;
        int asw = (arow & 7) << 3;
        bf16x8 aq0 = *(const bf16x8*)&Qw_s[arow * 64 + ((quad * 8) ^ asw)];
        bf16x8 aq1 = *(const bf16x8*)&Qw_s[arow * 64 + ((32 + quad * 8) ^ asw)];
        f32x4 s[8];
        #pragma unroll
        for (int ni = 0; ni < 8; ni++) {
            int krow = ni * 16 + l16;
            int ksw = (krow & 7) << 3;
            bf16x8 b0 = *(const bf16x8*)&K_s[krow * 64 + ((quad * 8) ^ ksw)];
            bf16x8 b1 = *(const bf16x8*)&K_s[krow * 64 + ((32 + quad * 8) ^ ksw)];
            f32x4 z = {};
            z = __builtin_amdgcn_mfma_f32_16x16x32_bf16(aq0, b0, z, 0, 0, 0);
            s[ni] = __builtin_amdgcn_mfma_f32_16x16x32_bf16(aq1, b1, z, 0, 0, 0);
        }

        // S = (AC + BD) * scale; causal mask only in last tile
        bool last = (jt == nt - 1);
        #pragma unroll
        for (int reg = 0; reg < 4; reg++) {
            int rl = quad * 4 + reg;
            int rsw = (rl & 7) << 3;
            #pragma unroll
            for (int ni = 0; ni < 8; ni++) {
                int c = ni * 16 + l16;
                float bd = b2f(BD_s[(wm + rl) * 128 + (c ^ rsw)]);
                float v = (s[ni][reg] + bd) * 0.125f;
                if (last && (j0 + c > i0 + wm + rl + 512)) v = -1e30f;
                s[ni][reg] = v;
            }
        }

        // online softmax per owned row
        #pragma unroll
        for (int reg = 0; reg < 4; reg++) {
            float tm = s[0][reg];
            #pragma unroll
            for (int ni = 1; ni < 8; ni++) tm = fmaxf(tm, s[ni][reg]);
            #pragma unroll
            for (int off = 1; off < 16; off <<= 1) tm = fmaxf(tm, __shfl_xor(tm, off, 64));
            float mn = fmaxf(m_run[reg], tm);
            float alpha = __expf(m_run[reg] - mn);
            m_run[reg] = mn;
            float ts = 0.f;
            #pragma unroll
            for (int ni = 0; ni < 8; ni++) {
                float p = __expf(s[ni][reg] - mn);
                s[ni][reg] = p;
                ts += p;
            }
            #pragma unroll
            for (int off = 1; off < 16; off <<= 1) ts += __shfl_xor(ts, off, 64);
            l_run[reg] = l_run[reg] * alpha + ts;
            #pragma unroll
            for (int di = 0; di < 4; di++) o[di][reg] *= alpha;
        }

        // write P (bf16) into BD_s (per-wave-private rows)
        #pragma unroll
        for (int reg = 0; reg < 4; reg++) {
            int rl = quad * 4 + reg;
            int rsw = (rl & 7) << 3;
            #pragma unroll
            for (int ni = 0; ni < 8; ni++) {
                int c = ni * 16 + l16;
                BD_s[(wm + rl) * 128 + (c ^ rsw)] = f2b(s[ni][reg]);
            }
        }

        // PV: O += P @ V
        #pragma unroll
        for (int kk = 0; kk < 4; kk++) {
            int prow = wm + l16;
            bf16x8 ap = *(const bf16x8*)&BD_s[prow * 128 + ((kk * 32 + quad * 8) ^ ((prow & 7) << 3))];
            #pragma unroll
            for (int di = 0; di < 4; di++) {
                int vr = di * 16 + l16;
                bf16x8 bv = *(const bf16x8*)&Vt_s[vr * 128 + ((kk * 32 + quad * 8) ^ ((vr & 7) << 3))];
                o[di] = __builtin_amdgcn_mfma_f32_16x16x32_bf16(ap, bv, o[di], 0, 0, 0);
            }
        }
    }

    // epilogue: normalize and write bf16 vec
    #pragma unroll
    for (int reg = 0; reg < 4; reg++) {
        float inv = 1.0f / l_run[reg];
        int r = i0 + wm + quad * 4 + reg;
        #pragma unroll
        for (int di = 0; di < 4; di++) {
            vecb[(size_t)(r * 8 + b) * 1024 + n * 64 + di * 16 + l16] = f2b(o[di][reg] * inv);
        }
    }
}

// ---------------------------------------------------------------------------
// Residual add + P split-K partials (+bias) + LayerNorm; emits fp32 AND bf16.
template <int P, bool BIAS>
__global__ __launch_bounds__(256) void add_lnp(const float* __restrict__ x,
                                               const float* __restrict__ p,
                                               const float* __restrict__ bias,
                                               const float* __restrict__ g,
                                               const float* __restrict__ bb,
                                               float* __restrict__ outf,
                                               unsigned short* __restrict__ outb) {
    const size_t S = (size_t)NROW * DM;
    int row = blockIdx.x;
    int t = threadIdx.x;
    __shared__ float rs[256], rq[256];
    float v[4];
    float s = 0.f, sq = 0.f;
    #pragma unroll
    for (int u = 0; u < 4; u++) {
        int c = t + u * 256;
        size_t idx = (size_t)row * DM + c;
        float val = x[idx];
        if (BIAS) val += bias[c];
        #pragma unroll
        for (int k = 0; k < P; k++) val += p[(size_t)k * S + idx];
        v[u] = val;
        s += val;
        sq += val * val;
    }
    rs[t] = s;
    rq[t] = sq;
    __syncthreads();
    for (int off = 128; off > 0; off >>= 1) {
        if (t < off) { rs[t] += rs[t + off]; rq[t] += rq[t + off]; }
        __syncthreads();
    }
    float mu = rs[0] * (1.0f / 1024.0f);
    float var = rq[0] * (1.0f / 1024.0f) - mu * mu;
    float rstd = rsqrtf(var + 1e-5f);
    #pragma unroll
    for (int u = 0; u < 4; u++) {
        int c = t + u * 256;
        size_t idx = (size_t)row * DM + c;
        float o = (v[u] - mu) * rstd * g[c] + bb[c];
        outf[idx] = o;
        outb[idx] = f2b(o);
    }
}

// ---------------------------------------------------------------------------
// Target logit from bf16 operands
__global__ __launch_bounds__(256) void tgt_logit_bf(const unsigned short* __restrict__ core,
                                                    const unsigned short* __restrict__ emb,
                                                    const int* __restrict__ target,
                                                    float* __restrict__ out) {
    int row = blockIdx.x;
    int t = threadIdx.x;
    __shared__ float red[256];
    int tok = target[row];
    const unsigned short* a = core + (size_t)row * DM;
    const unsigned short* e = emb + (size_t)tok * DM;
    float s = 0.f;
    #pragma unroll
    for (int u = 0; u < 4; u++) {
        int c = t + u * 256;
        s += b2f(a[c]) * b2f(e[c]);
    }
    red[t] = s;
    __syncthreads();
    for (int off = 128; off > 0; off >>= 1) {
        if (t < off) red[t] += red[t + off];
        __syncthreads();
    }
    if (t == 0) out[row] = red[0];
}

// ---------------------------------------------------------------------------
// Final LSE reduce: loss[row] = max + log(sum) - ltgt[row]
__global__ __launch_bounds__(256) void lse_reduce_kernel(const float* __restrict__ pmax,
                                                         const float* __restrict__ psum,
                                                         const float* __restrict__ ltgt,
                                                         float* __restrict__ loss) {
    int row = blockIdx.x;
    int t = threadIdx.x;
    __shared__ float red[256];
    float m = -1e30f;
    for (int u = t; u < VTILES; u += 256) m = fmaxf(m, pmax[(size_t)row * VTILES + u]);
    red[t] = m;
    __syncthreads();
    for (int off = 128; off > 0; off >>= 1) {
        if (t < off) red[t] = fmaxf(red[t], red[t + off]);
        __syncthreads();
    }
    float M = red[0];
    __syncthreads();
    float s = 0.f;
    for (int u = t; u < VTILES; u += 256)
        s += psum[(size_t)row * VTILES + u] * __expf(pmax[(size_t)row * VTILES + u] - M);
    red[t] = s;
    __syncthreads();
    for (int off = 128; off > 0; off >>= 1) {
        if (t < off) red[t] += red[t + off];
        __syncthreads();
    }
    if (t == 0) loss[row] = M + logf(red[0]) - ltgt[row];
}

// ---------------------------------------------------------------------------
extern "C" void kernel_launch(void* const* d_in, const int* in_sizes, int n_in,
                              void* d_out, int out_size, void* d_ws, size_t ws_size,
                              hipStream_t stream) {
    const int*   data   = (const int*)d_in[0];
    const int*   target = (const int*)d_in[1];
    const float* memory = (const float*)d_in[2];
    const float* embW   = (const float*)d_in[3];
    const float* rwb    = (const float*)d_in[4];
    const float* rrb    = (const float*)d_in[5];
    const float* Wq     = (const float*)d_in[6];
    const float* Wkv    = (const float*)d_in[7];
    const float* Wr     = (const float*)d_in[8];
    const float* Wo     = (const float*)d_in[9];
    const float* W1     = (const float*)d_in[10];
    const float* b1     = (const float*)d_in[11];
    const float* W2     = (const float*)d_in[12];
    const float* b2     = (const float*)d_in[13];
    const float* ln1g   = (const float*)d_in[14];
    const float* ln1b   = (const float*)d_in[15];
    const float* ln2g   = (const float*)d_in[16];
    const float* ln2b   = (const float*)d_in[17];

    float* out  = (float*)d_out;
    float* loss = out;                 // [512,8]
    float* hids = out + 4096;          // 6 x [512,8,1024] = new_mems

    const size_t SZ_CORE = (size_t)NROW * DM;

    // Workspace layout (MiB offsets; phase-aliased; max use 198 MiB)
    //   0-  2: posb (persistent)
    //   2- 14: rkball (persistent, all-layer r_k bf16 [1024][6144])
    //  14- 22: qw_b          | phase-B: wT (weight transposes)
    //  22- 30: qr_b          | phase-B: cmidb (bf16 of cmid)
    //  30- 38: wTA (Wq|Wkv^T)| flash out vecb | L5 LN fp32 scratch
    //  38- 54: Kh            | phase-B: Wo partials [0]
    //  54- 70: Vth           | phase-B: Wo partials [1]
    //  70-198: Bt            | 70-78 memb, 78-86 cinb (aliased in Bt head)
    //  86-102: cmid          | startup: wrT (86-98) | final: embWb (86-152)
    // 102-134: h1b
    // 134-198: w2p (4x fp32 split-K partials)
    // 152-162: pmax   162-172: psum   172-: ltgt   (final phase)
    const size_t MB = 1024 * 1024;
    char* base = (char*)d_ws;
    unsigned short* posb   = (unsigned short*)(base);
    unsigned short* rkball = (unsigned short*)(base + 2 * MB);
    unsigned short* qw_b   = (unsigned short*)(base + 14 * MB);
    unsigned short* qr_b   = (unsigned short*)(base + 22 * MB);
    unsigned short* wTA    = (unsigned short*)(base + 30 * MB);
    unsigned short* vecb   = (unsigned short*)(base + 30 * MB);
    unsigned short* Kh     = (unsigned short*)(base + 38 * MB);
    unsigned short* Vth    = (unsigned short*)(base + 54 * MB);
    unsigned short* Bt     = (unsigned short*)(base + 70 * MB);
    unsigned short* memb   = (unsigned short*)(base + 70 * MB);
    unsigned short* cinb   = (unsigned short*)(base + 78 * MB);
    float*          cmid   = (float*)(base + 86 * MB);
    unsigned short* wrT    = (unsigned short*)(base + 86 * MB);
    unsigned short* wT     = (unsigned short*)(base + 14 * MB);
    unsigned short* cmidb  = (unsigned short*)(base + 22 * MB);
    float*          wop    = (float*)(base + 38 * MB);
    unsigned short* h1b    = (unsigned short*)(base + 102 * MB);
    float*          w2p    = (float*)(base + 134 * MB);
    float*          lnscr  = (float*)(base + 30 * MB);
    unsigned short* embWb  = (unsigned short*)(base + 86 * MB);
    float*          pmax   = (float*)(base + 152 * MB);
    float*          psum   = (float*)(base + 162 * MB);
    float*          ltgt   = (float*)(base + 172 * MB);
    unsigned short* corefnb = cinb;   // L5 LN writes bf16 core here

    posb_kernel<<<KLEN, 256, 0, stream>>>(posb);
    gather_emb<<<NROW, 256, 0, stream>>>(data, embW, hids, cinb);  // hids[0] + bf16

    // r_k for ALL layers in one GEMM: rkball[j][L*1024+d] = (pos @ Wr[L])[j][d]
    for (int L = 0; L < 6; L++)
        castT_kernel<<<dim3(32, 32), 256, 0, stream>>>(
            Wr + (size_t)L * DM * DM, wrT + (size_t)L * DM * DM, DM, DM);
    gemm_bt<false, false, true><<<dim3(48, 8), 256, 0, stream>>>(
        posb, wrT, nullptr, rkball, KLEN, 6 * DM, DM);

    for (int L = 0; L < 6; L++) {
        const float* cin = hids + (size_t)L * SZ_CORE;
        float* coutf = (L < 5) ? (hids + (size_t)(L + 1) * SZ_CORE) : lnscr;

        // memb = bf16(mem[L]); cinb already present (prev add_lnp / gather)
        cast_bf16<<<4096, 256, 0, stream>>>(memory + (size_t)L * SZ_CORE, memb, 1 << 20);

        // fused [q|kv] = xmem @ [Wq|Wkv] with layout-scatter epilogue
        castT_kernel<<<dim3(32, 32), 256, 0, stream>>>(Wq + (size_t)L * DM * DM, wTA, DM, DM);
        castT_kernel<<<dim3(64, 32), 256, 0, stream>>>(
            Wkv + (size_t)L * DM * 2 * DM, wTA + (size_t)DM * DM, DM, 2 * DM);
        kqv_gemm<<<dim3(24, 64), 256, 0, stream>>>(
            memb, wTA, rwb, rrb, qw_b, qr_b, Kh, Vth);

        // Btilde + fused flash
        bd_gemm<<<dim3(8, 32, 16), 256, 0, stream>>>(qr_b, rkball + (size_t)L * DM, 6 * DM, Bt);
        flash_attn<<<dim3(8, 8, 16), 256, 0, stream>>>(qw_b, Kh, Vth, Bt, vecb);

        // attn_out = vec @ Wo[L], split-K=2 partials
        castT_kernel<<<dim3(32, 32), 256, 0, stream>>>(Wo + (size_t)L * DM * DM, wT, DM, DM);
        gemm_bt<false, false, false, 2><<<dim3(8, 32, 2), 256, 0, stream>>>(
            vecb, wT, nullptr, wop, NROW, DM, DM);

        // core_mid = LN(cin + attn_out) -> cmid fp32 + cmidb bf16
        add_lnp<2, false><<<NROW, 256, 0, stream>>>(
            cin, wop, nullptr, ln1g + L * DM, ln1b + L * DM, cmid, cmidb);

        // h1 = relu(core_mid @ W1[L] + b1[L]) -> bf16
        castT_kernel<<<dim3(128, 32), 256, 0, stream>>>(W1 + (size_t)L * DM * DI, wT, DM, DI);
        gemm_bt<true, true, true><<<dim3(32, 32), 256, 0, stream>>>(
            cmidb, wT, b1 + (size_t)L * DI, h1b, NROW, DI, DM);

        // ff partials = h1 @ W2[L]  (K=4096, split-K=4)
        castT_kernel<<<dim3(32, 128), 256, 0, stream>>>(W2 + (size_t)L * DI * DM, wT, DI, DM);
        gemm_bt<false, false, false, 4><<<dim3(8, 32, 4), 256, 0, stream>>>(
            h1b, wT, nullptr, w2p, NROW, DM, DI);

        // core_out = LN(cmid + sum(partials) + b2) -> fp32 (hids) + bf16 (next cinb)
        add_lnp<4, true><<<NROW, 256, 0, stream>>>(
            cmid, w2p, b2 + (size_t)L * DM, ln2g + L * DM, ln2b + L * DM, coutf, cinb);
    }

    // Final: loss = LSE(core @ embW^T) - logit[target]; corefnb == cinb
    cast_bf16<<<32768, 256, 0, stream>>>(embW, embWb, (NTOK * DM) / 4);
    tgt_logit_bf<<<NROW, 256, 0, stream>>>(corefnb, embWb, target, ltgt);
    lse_gemm_mfma<<<dim3(32, 250), 256, 0, stream>>>(corefnb, embWb, pmax, psum);
    lse_reduce_kernel<<<NROW, 256, 0, stream>>>(pmax, psum, ltgt, loss);
}

// Round 5
// 3188.315 us; speedup vs baseline: 1.0959x; 1.0959x over previous
//
#include <hip/hip_runtime.h>
#include <hip/hip_bf16.h>
#include <math.h>

// Problem constants
#define QLEN   512
#define MLEN   512
#define KLEN   1024
#define BSZ    8
#define NH     16
#define DH     64
#define DM     1024
#define DI     4096
#define NTOK   32000
#define NROW   4096      // QLEN*BSZ
#define XROW   8192      // KLEN*BSZ
#define VTILES 500       // 32000/64

typedef __hip_bfloat16 bf16;
typedef __attribute__((ext_vector_type(8))) short bf16x8;
typedef __attribute__((ext_vector_type(4))) float f32x4;

__device__ __forceinline__ unsigned short f2b(float x) {
    union { float f; unsigned u; } a; a.f = x;
    unsigned r = a.u + 0x7fffu + ((a.u >> 16) & 1u);
    return (unsigned short)(r >> 16);
}
__device__ __forceinline__ float b2f(unsigned short h) {
    union { unsigned u; float f; } a; a.u = ((unsigned)h) << 16;
    return a.f;
}

__device__ __forceinline__ void gload_lds16(const void* g, void* l) {
    __builtin_amdgcn_global_load_lds(
        (const __attribute__((address_space(1))) unsigned int*)g,
        (__attribute__((address_space(3))) unsigned int*)l, 16, 0, 0);
}

// ---------------------------------------------------------------------------
// Shared BK=64 K-loop for all 128x128 MFMA GEMMs. 256 threads / 4 waves.
// LDS tiles As/Bs are [128 rows][64 cols] bf16, stored with per-row XOR
// swizzle: LDS[row][c] = global[row][c ^ (row&7)] (chunk units of 8 elems).
// Staging via global_load_lds with PRE-SWIZZLED global source (linear LDS
// dest, rule #21); fragment reads apply the same XOR -> 2-way banks (free).
// Caller precomputes Ag = A + (bm + srow)*lda + scol  where
//   srow = wave*32 + (lane>>3),  scol = ((lane&7) ^ (srow&7)) * 8.
__device__ __forceinline__ void kloop64(const unsigned short* __restrict__ Ag, int lda,
                                        const unsigned short* __restrict__ Bg, int ldb,
                                        unsigned short* As, unsigned short* Bs,
                                        int wave, int lane, int wm, int wn,
                                        int k0, int k1, f32x4 acc[4][4]) {
    int quad = lane >> 4, l16 = lane & 15, asw = l16 & 7;
    unsigned short* Al = As + (wave * 32) * 64;
    unsigned short* Bl = Bs + (wave * 32) * 64;
    for (int kt = k0; kt < k1; kt += 64) {
        #pragma unroll
        for (int k = 0; k < 4; k++) {
            gload_lds16(Ag + kt + (size_t)(k * 8) * lda, Al + (k * 8) * 64);
            gload_lds16(Bg + kt + (size_t)(k * 8) * ldb, Bl + (k * 8) * 64);
        }
        __syncthreads();
        #pragma unroll
        for (int kk = 0; kk < 2; kk++) {
            bf16x8 af[4], bfr[4];
            #pragma unroll
            for (int mi = 0; mi < 4; mi++)
                af[mi] = *(const bf16x8*)&As[(wm + mi * 16 + l16) * 64
                                             + (((kk * 4 + quad) ^ asw) * 8)];
            #pragma unroll
            for (int ni = 0; ni < 4; ni++)
                bfr[ni] = *(const bf16x8*)&Bs[(wn + ni * 16 + l16) * 64
                                              + (((kk * 4 + quad) ^ asw) * 8)];
            #pragma unroll
            for (int mi = 0; mi < 4; mi++)
                #pragma unroll
                for (int ni = 0; ni < 4; ni++)
                    acc[mi][ni] = __builtin_amdgcn_mfma_f32_16x16x32_bf16(
                        af[mi], bfr[ni], acc[mi][ni], 0, 0, 0);
        }
        __syncthreads();
    }
}

// ---------------------------------------------------------------------------
// Positional embedding directly in bf16: pos[j,d], pos_seq[j]=1023-j
__global__ __launch_bounds__(256) void posb_kernel(unsigned short* __restrict__ posb) {
    int j = blockIdx.x;
    int t = threadIdx.x;
    float p = (float)(1023 - j);
    #pragma unroll
    for (int u = 0; u < 4; u++) {
        int dcol = t + u * 256;
        int k = dcol & 511;
        float invf = expf(-((float)k) * (1.0f / 512.0f) * 9.210340371976184f);
        float a = p * invf;
        posb[j * DM + dcol] = f2b((dcol < 512) ? sinf(a) : cosf(a));
    }
}

// ---------------------------------------------------------------------------
// Embedding gather: out[row,:] = emb[data[row],:]; also bf16 copy for layer 0
__global__ __launch_bounds__(256) void gather_emb(const int* __restrict__ data,
                                                  const float* __restrict__ emb,
                                                  float* __restrict__ out,
                                                  unsigned short* __restrict__ outb) {
    int row = blockIdx.x;
    int t = threadIdx.x;
    int tok = data[row];
    float4 v = ((const float4*)(emb + (size_t)tok * DM))[t];
    ((float4*)(out + (size_t)row * DM))[t] = v;
    ushort4 o;
    o.x = f2b(v.x); o.y = f2b(v.y); o.z = f2b(v.z); o.w = f2b(v.w);
    ((ushort4*)(outb + (size_t)row * DM))[t] = o;
}

// ---------------------------------------------------------------------------
// fp32 -> bf16 cast, 4 elems/thread
__global__ __launch_bounds__(256) void cast_bf16(const float* __restrict__ src,
                                                 unsigned short* __restrict__ dst, int n4) {
    int i = blockIdx.x * 256 + threadIdx.x;
    if (i < n4) {
        float4 v = ((const float4*)src)[i];
        ushort4 o;
        o.x = f2b(v.x); o.y = f2b(v.y); o.z = f2b(v.z); o.w = f2b(v.w);
        ((ushort4*)dst)[i] = o;
    }
}

// ---------------------------------------------------------------------------
// Batched fp32 [K,N] -> bf16 [N,K] transpose+cast for up to 3 matrices.
// Flat grid; block id ranges select descriptor.
__global__ __launch_bounds__(256) void castT3(const float* __restrict__ s0,
                                              unsigned short* __restrict__ d0, int K0, int N0,
                                              const float* __restrict__ s1,
                                              unsigned short* __restrict__ d1, int K1, int N1,
                                              const float* __restrict__ s2,
                                              unsigned short* __restrict__ d2, int K2, int N2) {
    int id = blockIdx.x;
    const float* src; unsigned short* dst; int K, N;
    int n0 = (N0 >> 5) * (K0 >> 5), n1 = (N1 >> 5) * (K1 >> 5);
    if (id < n0)           { src = s0; dst = d0; K = K0; N = N0; }
    else if (id < n0 + n1) { id -= n0; src = s1; dst = d1; K = K1; N = N1; }
    else                   { id -= n0 + n1; src = s2; dst = d2; K = K2; N = N2; }
    __shared__ float T[32][33];
    int t = threadIdx.x;
    int bx = id % (N >> 5), by = id / (N >> 5);
    int k0 = by * 32, nc0 = bx * 32;
    int r = t >> 3, c4 = (t & 7) * 4;
    float4 v = *(const float4*)(src + (size_t)(k0 + r) * N + nc0 + c4);
    T[r][c4 + 0] = v.x; T[r][c4 + 1] = v.y; T[r][c4 + 2] = v.z; T[r][c4 + 3] = v.w;
    __syncthreads();
    ushort4 o;
    o.x = f2b(T[c4 + 0][r]); o.y = f2b(T[c4 + 1][r]);
    o.z = f2b(T[c4 + 2][r]); o.w = f2b(T[c4 + 3][r]);
    *(ushort4*)(dst + (size_t)(nc0 + r) * K + k0 + c4) = o;
}

// ---------------------------------------------------------------------------
// bf16 MFMA GEMM: C[M,N] = A[M,K] @ B[N,K]^T. Both operands K-major bf16.
// SPLITK>1: blockIdx.z handles K-chunk z, writes fp32 partial at z*M*N.
// K (and K/SPLITK) must be multiples of 64.
template <bool BIAS, bool RELU, bool OUTBF16, int SPLITK = 1>
__global__ __launch_bounds__(256) void gemm_bt(const unsigned short* __restrict__ A,
                                               const unsigned short* __restrict__ B,
                                               const float* __restrict__ bias,
                                               void* __restrict__ Cout,
                                               int M, int N, int K) {
    __shared__ unsigned short As[128 * 64];
    __shared__ unsigned short Bs[128 * 64];
    int t = threadIdx.x;
    int wave = t >> 6, lane = t & 63;
    int bm = blockIdx.y * 128, bn = blockIdx.x * 128;
    int wm = (wave >> 1) * 64, wn = (wave & 1) * 64;
    int quad = lane >> 4, l16 = lane & 15;

    f32x4 acc[4][4] = {};

    int srow = wave * 32 + (lane >> 3);
    int scol = ((lane & 7) ^ (srow & 7)) * 8;
    const unsigned short* Ag = A + (size_t)(bm + srow) * K + scol;
    const unsigned short* Bg = B + (size_t)(bn + srow) * K + scol;

    int kchunk = K / SPLITK;
    int k0 = (SPLITK > 1) ? blockIdx.z * kchunk : 0;
    kloop64(Ag, K, Bg, K, As, Bs, wave, lane, wm, wn, k0, k0 + kchunk, acc);

    float* Cf = (float*)Cout + ((SPLITK > 1) ? (size_t)blockIdx.z * M * N : (size_t)0);
    #pragma unroll
    for (int mi = 0; mi < 4; mi++) {
        #pragma unroll
        for (int ni = 0; ni < 4; ni++) {
            int c = bn + wn + ni * 16 + l16;
            float bv = BIAS ? bias[c] : 0.0f;
            #pragma unroll
            for (int reg = 0; reg < 4; reg++) {
                int r = bm + wm + mi * 16 + quad * 4 + reg;
                float x = acc[mi][ni][reg];
                if (BIAS) x += bv;
                if (RELU) x = fmaxf(x, 0.0f);
                if (OUTBF16) ((unsigned short*)Cout)[(size_t)r * N + c] = f2b(x);
                else         Cf[(size_t)r * N + c] = x;
            }
        }
    }
}

// ---------------------------------------------------------------------------
// Fused [q|kv] GEMM with layout-scatter epilogue. A = xmemb [8192][1024] bf16
// (rows j*8+b; rows>=4096 are core rows i*8+b). B = [Wq|Wkv]^T [3072][1024].
// Grid (24, 64): bn<8 -> q cols, 8..15 -> k cols, 16..23 -> v cols.
__global__ __launch_bounds__(256) void kqv_gemm(const unsigned short* __restrict__ A,
                                                const unsigned short* __restrict__ B,
                                                const float* __restrict__ rwb,
                                                const float* __restrict__ rrb,
                                                unsigned short* __restrict__ qw,
                                                unsigned short* __restrict__ qr,
                                                unsigned short* __restrict__ Kh,
                                                unsigned short* __restrict__ Vth) {
    int cls = blockIdx.x >> 3;                 // 0=q, 1=k, 2=v
    if (cls == 0 && blockIdx.y < 32) return;   // q for memory rows: unused
    __shared__ unsigned short As[128 * 64];
    __shared__ unsigned short Bs[128 * 64];
    const int K = 1024;
    int t = threadIdx.x;
    int wave = t >> 6, lane = t & 63;
    int bm = blockIdx.y * 128, bn = blockIdx.x * 128;
    int wm = (wave >> 1) * 64, wn = (wave & 1) * 64;
    int quad = lane >> 4, l16 = lane & 15;

    f32x4 acc[4][4] = {};

    int srow = wave * 32 + (lane >> 3);
    int scol = ((lane & 7) ^ (srow & 7)) * 8;
    const unsigned short* Ag = A + (size_t)(bm + srow) * K + scol;
    const unsigned short* Bg = B + (size_t)(bn + srow) * K + scol;
    kloop64(Ag, K, Bg, K, As, Bs, wave, lane, wm, wn, 0, K, acc);

    if (cls == 0) {
        #pragma unroll
        for (int ni = 0; ni < 4; ni++) {
            int c = bn + wn + ni * 16 + l16;          // 0..1023
            float wv = rwb[c], rv = rrb[c];
            #pragma unroll
            for (int mi = 0; mi < 4; mi++) {
                #pragma unroll
                for (int reg = 0; reg < 4; reg++) {
                    int r = bm + wm + mi * 16 + quad * 4 + reg;
                    int row = r - 4096;               // i*8+b
                    int i = row >> 3;
                    float x = acc[mi][ni][reg];
                    qr[(size_t)row * DM + c] = f2b(x + rv);
                    qw[(size_t)row * DM + (c & ~63) + ((c & 63) ^ ((i & 7) << 3))] = f2b(x + wv);
                }
            }
        }
    } else if (cls == 1) {
        #pragma unroll
        for (int ni = 0; ni < 4; ni++) {
            int cc = bn + wn + ni * 16 + l16 - 1024;
            int d = cc & 63, hb = cc >> 6;
            #pragma unroll
            for (int mi = 0; mi < 4; mi++) {
                #pragma unroll
                for (int reg = 0; reg < 4; reg++) {
                    int r = bm + wm + mi * 16 + quad * 4 + reg;
                    int j = r >> 3, nb = hb * 8 + (r & 7);
                    Kh[(size_t)nb * 65536 + (size_t)j * 64 + (d ^ ((j & 7) << 3))] =
                        f2b(acc[mi][ni][reg]);
                }
            }
        }
    } else {
        #pragma unroll
        for (int ni = 0; ni < 4; ni++) {
            int cc = bn + wn + ni * 16 + l16 - 2048;
            int d = cc & 63, hb = cc >> 6;
            #pragma unroll
            for (int mi = 0; mi < 4; mi++) {
                #pragma unroll
                for (int reg = 0; reg < 4; reg++) {
                    int r = bm + wm + mi * 16 + quad * 4 + reg;
                    int j = r >> 3, nb = hb * 8 + (r & 7);
                    Vth[(size_t)nb * 65536 + (size_t)d * 1024
                        + (j & ~127) + ((j & 127) ^ ((d & 7) << 3))] =
                        f2b(acc[mi][ni][reg]);
                }
            }
        }
    }
}

// ---------------------------------------------------------------------------
// Fused logits + partial LSE. Grid (bm=32, bn=250) -- bm-fastest so co-resident
// blocks share one B-strip (L2) and re-read only A (8MB, L3-resident).
__global__ __launch_bounds__(256) void lse_gemm_mfma(const unsigned short* __restrict__ A,
                                                     const unsigned short* __restrict__ B,
                                                     float* __restrict__ pmax,
                                                     float* __restrict__ psum) {
    __shared__ unsigned short As[128 * 64];
    __shared__ unsigned short Bs[128 * 64];
    int t = threadIdx.x;
    int wave = t >> 6, lane = t & 63;
    int bm = blockIdx.x * 128, bn = blockIdx.y * 128;
    int wm = (wave >> 1) * 64, wn = (wave & 1) * 64;
    int quad = lane >> 4, l16 = lane & 15;
    const int K = 1024;

    f32x4 acc[4][4] = {};

    int srow = wave * 32 + (lane >> 3);
    int scol = ((lane & 7) ^ (srow & 7)) * 8;
    const unsigned short* Ag = A + (size_t)(bm + srow) * K + scol;
    const unsigned short* Bg = B + (size_t)(bn + srow) * K + scol;
    kloop64(Ag, K, Bg, K, As, Bs, wave, lane, wm, wn, 0, K, acc);

    int vt = blockIdx.y * 2 + (wave & 1);
    #pragma unroll
    for (int mi = 0; mi < 4; mi++) {
        #pragma unroll
        for (int reg = 0; reg < 4; reg++) {
            float m = -1e30f;
            #pragma unroll
            for (int ni = 0; ni < 4; ni++) m = fmaxf(m, acc[mi][ni][reg]);
            #pragma unroll
            for (int off = 1; off < 16; off <<= 1) m = fmaxf(m, __shfl_xor(m, off, 64));
            float s = 0.0f;
            #pragma unroll
            for (int ni = 0; ni < 4; ni++) s += __expf(acc[mi][ni][reg] - m);
            #pragma unroll
            for (int off = 1; off < 16; off <<= 1) s += __shfl_xor(s, off, 64);
            if (l16 == 0) {
                int r = bm + wm + mi * 16 + quad * 4 + reg;
                pmax[(size_t)r * VTILES + vt] = m;
                psum[(size_t)r * VTILES + vt] = s;
            }
        }
    }
}

// ---------------------------------------------------------------------------
// bd_gemm: Btilde = (q + r_r_bias) @ r_k^T per head, written PRE-SHIFTED.
// B operand has row stride ldb (packed multi-layer r_k). grid (8, 32, 16), K=64.
__global__ __launch_bounds__(256) void bd_gemm(const unsigned short* __restrict__ A,
                                               const unsigned short* __restrict__ B,
                                               int ldb,
                                               unsigned short* __restrict__ Bt) {
    __shared__ unsigned short As[128 * 64];
    __shared__ unsigned short Bs[128 * 64];
    int t = threadIdx.x;
    int wave = t >> 6, lane = t & 63;
    int bm = blockIdx.y * 128, bn = blockIdx.x * 128, n = blockIdx.z;
    int wm = (wave >> 1) * 64, wn = (wave & 1) * 64;
    int quad = lane >> 4, l16 = lane & 15;
    f32x4 acc[4][4] = {};
    int srow = wave * 32 + (lane >> 3);
    int scol = ((lane & 7) ^ (srow & 7)) * 8;
    const unsigned short* Ag = A + (size_t)(bm + srow) * DM + n * 64 + scol;
    const unsigned short* Bg = B + (size_t)(bn + srow) * ldb + n * 64 + scol;
    kloop64(Ag, DM, Bg, ldb, As, Bs, wave, lane, wm, wn, 0, 64, acc);

    #pragma unroll
    for (int mi = 0; mi < 4; mi++) {
        #pragma unroll
        for (int reg = 0; reg < 4; reg++) {
            int r = bm + wm + mi * 16 + quad * 4 + reg;
            int i = r >> 3;
            size_t rowbase = ((size_t)n * 4096 + r) * 1024;
            int sw = (i & 7) << 3;
            #pragma unroll
            for (int ni = 0; ni < 4; ni++) {
                int p = bn + wn + ni * 16 + l16;
                int j = p + i - 511;
                if ((unsigned)j < 1024u)
                    Bt[rowbase + (j & ~127) + ((j & 127) ^ sw)] = f2b(acc[mi][ni][reg]);
            }
        }
    }
}

// ---------------------------------------------------------------------------
// Fused flash attention, MFMA. Writes bf16 output directly.
__global__ __launch_bounds__(256) void flash_attn(const unsigned short* __restrict__ qw_b,
                                                  const unsigned short* __restrict__ Kh,
                                                  const unsigned short* __restrict__ Vth,
                                                  const unsigned short* __restrict__ Bt,
                                                  unsigned short* __restrict__ vecb) {
    int qb = blockIdx.x, b = blockIdx.y, n = blockIdx.z;
    int i0 = qb * 64, nb = n * 8 + b;
    int t = threadIdx.x, wave = t >> 6, lane = t & 63;
    int quad = lane >> 4, l16 = lane & 15;
    int wm = wave * 16;
    __shared__ unsigned short Qw_s[64 * 64];
    __shared__ unsigned short K_s[128 * 64];
    __shared__ unsigned short Vt_s[64 * 128];
    __shared__ unsigned short BD_s[64 * 128];   // aliased as P after consumption

    // stage Qw once (8KB)
    {
        const unsigned short* g = qw_b
            + (size_t)((i0 + wave * 16 + (lane >> 3)) * 8 + b) * DM + n * 64 + (lane & 7) * 8;
        unsigned short* l = Qw_s + (wave * 16) * 64;
        gload_lds16(g, l);
        gload_lds16(g + (size_t)64 * DM, l + 8 * 64);
    }

    f32x4 o[4] = {};
    float m_run[4] = { -1e30f, -1e30f, -1e30f, -1e30f };
    float l_run[4] = {};

    int nt = ((i0 + 575) >> 7) + 1;
    for (int jt = 0; jt < nt; jt++) {
        int j0 = jt * 128;
        __syncthreads();
        {   // K tile (16KB): rows wave*32..+32
            const unsigned short* g = Kh + (size_t)nb * 65536
                + (size_t)(j0 + wave * 32 + (lane >> 3)) * 64 + (lane & 7) * 8;
            unsigned short* l = K_s + (wave * 32) * 64;
            #pragma unroll
            for (int k = 0; k < 4; k++)
                gload_lds16(g + (size_t)k * 512, l + k * 512);
        }
        {   // Vt tile (16KB): d-rows wave*16..+16
            const unsigned short* g = Vth + (size_t)nb * 65536
                + (size_t)(wave * 16 + (lane >> 4)) * 1024 + j0 + (lane & 15) * 8;
            unsigned short* l = Vt_s + (wave * 16) * 128;
            #pragma unroll
            for (int k = 0; k < 4; k++)
                gload_lds16(g + (size_t)k * 4096, l + k * 512);
        }
        {   // BD tile (16KB): q-rows wave*16..+16
            const unsigned short* g = Bt
                + ((size_t)n * 4096 + (size_t)(i0 + wave * 16 + (lane >> 4)) * 8 + b) * 1024
                + j0 + (lane & 15) * 8;
            unsigned short* l = BD_s + (wave * 16) * 128;
            #pragma unroll
            for (int k = 0; k < 4; k++)
                gload_lds16(g + (size_t)k * 32768, l + k * 512);
        }
        __syncthreads();

        // AC = Qw @ K^T
        int arow = wm + l16;
        int asw = (arow & 7) << 3;
        bf16x8 aq0 = *(const bf16x8*)&Qw_s[arow * 64 + ((quad * 8) ^ asw)];
        bf16x8 aq1 = *(const bf16x8*)&Qw_s[arow * 64 + ((32 + quad * 8) ^ asw)];
        f32x4 s[8];
        #pragma unroll
        for (int ni = 0; ni < 8; ni++) {
            int krow = ni * 16 + l16;
            int ksw = (krow & 7) << 3;
            bf16x8 b0 = *(const bf16x8*)&K_s[krow * 64 + ((quad * 8) ^ ksw)];
            bf16x8 b1 = *(const bf16x8*)&K_s[krow * 64 + ((32 + quad * 8) ^ ksw)];
            f32x4 z = {};
            z = __builtin_amdgcn_mfma_f32_16x16x32_bf16(aq0, b0, z, 0, 0, 0);
            s[ni] = __builtin_amdgcn_mfma_f32_16x16x32_bf16(aq1, b1, z, 0, 0, 0);
        }

        // S = (AC + BD) * scale; causal mask only in last tile
        bool last = (jt == nt - 1);
        #pragma unroll
        for (int reg = 0; reg < 4; reg++) {
            int rl = quad * 4 + reg;
            int rsw = (rl & 7) << 3;
            #pragma unroll
            for (int ni = 0; ni < 8; ni++) {
                int c = ni * 16 + l16;
                float bd = b2f(BD_s[(wm + rl) * 128 + (c ^ rsw)]);
                float v = (s[ni][reg] + bd) * 0.125f;
                if (last && (j0 + c > i0 + wm + rl + 512)) v = -1e30f;
                s[ni][reg] = v;
            }
        }

        // online softmax per owned row
        #pragma unroll
        for (int reg = 0; reg < 4; reg++) {
            float tm = s[0][reg];
            #pragma unroll
            for (int ni = 1; ni < 8; ni++) tm = fmaxf(tm, s[ni][reg]);
            #pragma unroll
            for (int off = 1; off < 16; off <<= 1) tm = fmaxf(tm, __shfl_xor(tm, off, 64));
            float mn = fmaxf(m_run[reg], tm);
            float alpha = __expf(m_run[reg] - mn);
            m_run[reg] = mn;
            float ts = 0.f;
            #pragma unroll
            for (int ni = 0; ni < 8; ni++) {
                float p = __expf(s[ni][reg] - mn);
                s[ni][reg] = p;
                ts += p;
            }
            #pragma unroll
            for (int off = 1; off < 16; off <<= 1) ts += __shfl_xor(ts, off, 64);
            l_run[reg] = l_run[reg] * alpha + ts;
            #pragma unroll
            for (int di = 0; di < 4; di++) o[di][reg] *= alpha;
        }

        // write P (bf16) into BD_s (per-wave-private rows)
        #pragma unroll
        for (int reg = 0; reg < 4; reg++) {
            int rl = quad * 4 + reg;
            int rsw = (rl & 7) << 3;
            #pragma unroll
            for (int ni = 0; ni < 8; ni++) {
                int c = ni * 16 + l16;
                BD_s[(wm + rl) * 128 + (c ^ rsw)] = f2b(s[ni][reg]);
            }
        }

        // PV: O += P @ V
        #pragma unroll
        for (int kk = 0; kk < 4; kk++) {
            int prow = wm + l16;
            bf16x8 ap = *(const bf16x8*)&BD_s[prow * 128 + ((kk * 32 + quad * 8) ^ ((prow & 7) << 3))];
            #pragma unroll
            for (int di = 0; di < 4; di++) {
                int vr = di * 16 + l16;
                bf16x8 bv = *(const bf16x8*)&Vt_s[vr * 128 + ((kk * 32 + quad * 8) ^ ((vr & 7) << 3))];
                o[di] = __builtin_amdgcn_mfma_f32_16x16x32_bf16(ap, bv, o[di], 0, 0, 0);
            }
        }
    }

    // epilogue: normalize and write bf16 vec
    #pragma unroll
    for (int reg = 0; reg < 4; reg++) {
        float inv = 1.0f / l_run[reg];
        int r = i0 + wm + quad * 4 + reg;
        #pragma unroll
        for (int di = 0; di < 4; di++) {
            vecb[(size_t)(r * 8 + b) * 1024 + n * 64 + di * 16 + l16] = f2b(o[di][reg] * inv);
        }
    }
}

// ---------------------------------------------------------------------------
// Residual add + P split-K partials (+bias) + LayerNorm; emits fp32 (optional)
// AND bf16.
template <int P, bool BIAS>
__global__ __launch_bounds__(256) void add_lnp(const float* __restrict__ x,
                                               const float* __restrict__ p,
                                               const float* __restrict__ bias,
                                               const float* __restrict__ g,
                                               const float* __restrict__ bb,
                                               float* __restrict__ outf,
                                               unsigned short* __restrict__ outb) {
    const size_t S = (size_t)NROW * DM;
    int row = blockIdx.x;
    int t = threadIdx.x;
    __shared__ float rs[256], rq[256];
    float v[4];
    float s = 0.f, sq = 0.f;
    #pragma unroll
    for (int u = 0; u < 4; u++) {
        int c = t + u * 256;
        size_t idx = (size_t)row * DM + c;
        float val = x[idx];
        if (BIAS) val += bias[c];
        #pragma unroll
        for (int k = 0; k < P; k++) val += p[(size_t)k * S + idx];
        v[u] = val;
        s += val;
        sq += val * val;
    }
    rs[t] = s;
    rq[t] = sq;
    __syncthreads();
    for (int off = 128; off > 0; off >>= 1) {
        if (t < off) { rs[t] += rs[t + off]; rq[t] += rq[t + off]; }
        __syncthreads();
    }
    float mu = rs[0] * (1.0f / 1024.0f);
    float var = rq[0] * (1.0f / 1024.0f) - mu * mu;
    float rstd = rsqrtf(var + 1e-5f);
    #pragma unroll
    for (int u = 0; u < 4; u++) {
        int c = t + u * 256;
        size_t idx = (size_t)row * DM + c;
        float o = (v[u] - mu) * rstd * g[c] + bb[c];
        if (outf) outf[idx] = o;
        outb[idx] = f2b(o);
    }
}

// ---------------------------------------------------------------------------
// Target logit from bf16 operands
__global__ __launch_bounds__(256) void tgt_logit_bf(const unsigned short* __restrict__ core,
                                                    const unsigned short* __restrict__ emb,
                                                    const int* __restrict__ target,
                                                    float* __restrict__ out) {
    int row = blockIdx.x;
    int t = threadIdx.x;
    __shared__ float red[256];
    int tok = target[row];
    const unsigned short* a = core + (size_t)row * DM;
    const unsigned short* e = emb + (size_t)tok * DM;
    float s = 0.f;
    #pragma unroll
    for (int u = 0; u < 4; u++) {
        int c = t + u * 256;
        s += b2f(a[c]) * b2f(e[c]);
    }
    red[t] = s;
    __syncthreads();
    for (int off = 128; off > 0; off >>= 1) {
        if (t < off) red[t] += red[t + off];
        __syncthreads();
    }
    if (t == 0) out[row] = red[0];
}

// ---------------------------------------------------------------------------
// Final LSE reduce: loss[row] = max + log(sum) - ltgt[row]
__global__ __launch_bounds__(256) void lse_reduce_kernel(const float* __restrict__ pmax,
                                                         const float* __restrict__ psum,
                                                         const float* __restrict__ ltgt,
                                                         float* __restrict__ loss) {
    int row = blockIdx.x;
    int t = threadIdx.x;
    __shared__ float red[256];
    float m = -1e30f;
    for (int u = t; u < VTILES; u += 256) m = fmaxf(m, pmax[(size_t)row * VTILES + u]);
    red[t] = m;
    __syncthreads();
    for (int off = 128; off > 0; off >>= 1) {
        if (t < off) red[t] = fmaxf(red[t], red[t + off]);
        __syncthreads();
    }
    float M = red[0];
    __syncthreads();
    float s = 0.f;
    for (int u = t; u < VTILES; u += 256)
        s += psum[(size_t)row * VTILES + u] * __expf(pmax[(size_t)row * VTILES + u] - M);
    red[t] = s;
    __syncthreads();
    for (int off = 128; off > 0; off >>= 1) {
        if (t < off) red[t] += red[t + off];
        __syncthreads();
    }
    if (t == 0) loss[row] = M + logf(red[0]) - ltgt[row];
}

// ---------------------------------------------------------------------------
extern "C" void kernel_launch(void* const* d_in, const int* in_sizes, int n_in,
                              void* d_out, int out_size, void* d_ws, size_t ws_size,
                              hipStream_t stream) {
    const int*   data   = (const int*)d_in[0];
    const int*   target = (const int*)d_in[1];
    const float* memory = (const float*)d_in[2];
    const float* embW   = (const float*)d_in[3];
    const float* rwb    = (const float*)d_in[4];
    const float* rrb    = (const float*)d_in[5];
    const float* Wq     = (const float*)d_in[6];
    const float* Wkv    = (const float*)d_in[7];
    const float* Wr     = (const float*)d_in[8];
    const float* Wo     = (const float*)d_in[9];
    const float* W1     = (const float*)d_in[10];
    const float* b1     = (const float*)d_in[11];
    const float* W2     = (const float*)d_in[12];
    const float* b2     = (const float*)d_in[13];
    const float* ln1g   = (const float*)d_in[14];
    const float* ln1b   = (const float*)d_in[15];
    const float* ln2g   = (const float*)d_in[16];
    const float* ln2b   = (const float*)d_in[17];

    float* out  = (float*)d_out;
    float* loss = out;                 // [512,8]
    float* hids = out + 4096;          // 6 x [512,8,1024] = new_mems

    const size_t SZ_CORE = (size_t)NROW * DM;

    // Workspace layout (MiB offsets; phase-aliased; max use 198 MiB)
    // persistent:  0-2 posb | 2-14 rkball
    // phase-A:    14-22 qw | 22-30 qr | 30-38 wTA/vecb | 38-54 Kh | 54-70 Vth
    //             70-198 Bt (70-78 memb, 78-86 cinb live before bd_gemm)
    // phase-B:    14-22 W1T | 22-30 W2T | 38-70 wop(2x16MB) | 86-102 cmid
    //             102-134 h1b | 134-136 WoT (dead before w2p) | 134-166 w2p
    //             166-174 cmidb
    // startup:    86-98 wrT (dead after rk gemm)
    // final:      86-149 embWb | 152-162 pmax | 162-172 psum | 172- ltgt
    const size_t MB = 1024 * 1024;
    char* base = (char*)d_ws;
    unsigned short* posb   = (unsigned short*)(base);
    unsigned short* rkball = (unsigned short*)(base + 2 * MB);
    unsigned short* qw_b   = (unsigned short*)(base + 14 * MB);
    unsigned short* qr_b   = (unsigned short*)(base + 22 * MB);
    unsigned short* wTA    = (unsigned short*)(base + 30 * MB);
    unsigned short* vecb   = (unsigned short*)(base + 30 * MB);
    unsigned short* Kh     = (unsigned short*)(base + 38 * MB);
    unsigned short* Vth    = (unsigned short*)(base + 54 * MB);
    unsigned short* Bt     = (unsigned short*)(base + 70 * MB);
    unsigned short* memb   = (unsigned short*)(base + 70 * MB);
    unsigned short* cinb   = (unsigned short*)(base + 78 * MB);
    float*          cmid   = (float*)(base + 86 * MB);
    unsigned short* wrT    = (unsigned short*)(base + 86 * MB);
    unsigned short* W1T    = (unsigned short*)(base + 14 * MB);
    unsigned short* W2T    = (unsigned short*)(base + 22 * MB);
    unsigned short* WoT    = (unsigned short*)(base + 134 * MB);
    float*          wop    = (float*)(base + 38 * MB);
    unsigned short* h1b    = (unsigned short*)(base + 102 * MB);
    float*          w2p    = (float*)(base + 134 * MB);
    unsigned short* cmidb  = (unsigned short*)(base + 166 * MB);
    unsigned short* embWb  = (unsigned short*)(base + 86 * MB);
    float*          pmax   = (float*)(base + 152 * MB);
    float*          psum   = (float*)(base + 162 * MB);
    float*          ltgt   = (float*)(base + 172 * MB);
    unsigned short* corefnb = cinb;   // L5 LN writes bf16 core here

    posb_kernel<<<KLEN, 256, 0, stream>>>(posb);
    gather_emb<<<NROW, 256, 0, stream>>>(data, embW, hids, cinb);  // hids[0] + bf16

    // r_k for ALL layers in one GEMM: rkball[j][L*1024+d] = (pos @ Wr[L])[j][d]
    castT3<<<3072, 256, 0, stream>>>(
        Wr,                      wrT,                      DM, DM,
        Wr + (size_t)1 * DM * DM, wrT + (size_t)1 * DM * DM, DM, DM,
        Wr + (size_t)2 * DM * DM, wrT + (size_t)2 * DM * DM, DM, DM);
    castT3<<<3072, 256, 0, stream>>>(
        Wr + (size_t)3 * DM * DM, wrT + (size_t)3 * DM * DM, DM, DM,
        Wr + (size_t)4 * DM * DM, wrT + (size_t)4 * DM * DM, DM, DM,
        Wr + (size_t)5 * DM * DM, wrT + (size_t)5 * DM * DM, DM, DM);
    gemm_bt<false, false, true><<<dim3(48, 8), 256, 0, stream>>>(
        posb, wrT, nullptr, rkball, KLEN, 6 * DM, DM);

    for (int L = 0; L < 6; L++) {
        const float* cin = hids + (size_t)L * SZ_CORE;
        float* coutf = (L < 5) ? (hids + (size_t)(L + 1) * SZ_CORE) : nullptr;

        // memb = bf16(mem[L]); cinb already present (prev add_lnp / gather)
        cast_bf16<<<4096, 256, 0, stream>>>(memory + (size_t)L * SZ_CORE, memb, 1 << 20);

        // [Wq|Wkv]^T -> wTA (one batched transpose launch)
        castT3<<<3072, 256, 0, stream>>>(
            Wq + (size_t)L * DM * DM,      wTA,                    DM, DM,
            Wkv + (size_t)L * DM * 2 * DM, wTA + (size_t)DM * DM,  DM, 2 * DM,
            Wq, wTA, 32, 32);

        // fused [q|kv] = xmem @ [Wq|Wkv] with layout-scatter epilogue
        kqv_gemm<<<dim3(24, 64), 256, 0, stream>>>(
            memb, wTA, rwb, rrb, qw_b, qr_b, Kh, Vth);

        // Btilde + fused flash
        bd_gemm<<<dim3(8, 32, 16), 256, 0, stream>>>(qr_b, rkball + (size_t)L * DM, 6 * DM, Bt);
        flash_attn<<<dim3(8, 8, 16), 256, 0, stream>>>(qw_b, Kh, Vth, Bt, vecb);

        // Wo/W1/W2 transposes in one batched launch (regions free post-flash)
        castT3<<<9216, 256, 0, stream>>>(
            Wo + (size_t)L * DM * DM, WoT, DM, DM,
            W1 + (size_t)L * DM * DI, W1T, DM, DI,
            W2 + (size_t)L * DI * DM, W2T, DI, DM);

        // attn_out = vec @ Wo[L], split-K=2 partials
        gemm_bt<false, false, false, 2><<<dim3(8, 32, 2), 256, 0, stream>>>(
            vecb, WoT, nullptr, wop, NROW, DM, DM);

        // core_mid = LN(cin + attn_out) -> cmid fp32 + cmidb bf16
        add_lnp<2, false><<<NROW, 256, 0, stream>>>(
            cin, wop, nullptr, ln1g + L * DM, ln1b + L * DM, cmid, cmidb);

        // h1 = relu(core_mid @ W1[L] + b1[L]) -> bf16
        gemm_bt<true, true, true><<<dim3(32, 32), 256, 0, stream>>>(
            cmidb, W1T, b1 + (size_t)L * DI, h1b, NROW, DI, DM);

        // ff partials = h1 @ W2[L]  (K=4096, split-K=2)
        gemm_bt<false, false, false, 2><<<dim3(8, 32, 2), 256, 0, stream>>>(
            h1b, W2T, nullptr, w2p, NROW, DM, DI);

        // core_out = LN(cmid + sum(partials) + b2) -> fp32 (hids, skip at L5)
        // + bf16 (next cinb)
        add_lnp<2, true><<<NROW, 256, 0, stream>>>(
            cmid, w2p, b2 + (size_t)L * DM, ln2g + L * DM, ln2b + L * DM, coutf, cinb);
    }

    // Final: loss = LSE(core @ embW^T) - logit[target]; corefnb == cinb
    cast_bf16<<<32768, 256, 0, stream>>>(embW, embWb, (NTOK * DM) / 4);
    tgt_logit_bf<<<NROW, 256, 0, stream>>>(corefnb, embWb, target, ltgt);
    lse_gemm_mfma<<<dim3(32, 250), 256, 0, stream>>>(corefnb, embWb, pmax, psum);
    lse_reduce_kernel<<<NROW, 256, 0, stream>>>(pmax, psum, ltgt, loss);
}